// Round 8
// baseline (23.844 us; speedup 1.0000x reference)
//
#include <hip/hip_runtime.h>

// HardUpsampling: seqs [N=16, T=2048, M=256] f32, durations [N, T] i32 in [0,4)
// out = concat( upsampled [N, L, M] f32 , lens [N] (written as f32) )
//
// Round 8: R7 single-kernel + tail elimination.
//  - BLK_POS 16 -> 32 (4 waves x 8 positions): grid 3136 -> 1568 blocks,
//    all co-resident on 256 CUs (<= 2048 slots) -> one scheduling round,
//    no 1.53-round tail quantization (R7's remaining ~4us).
//  - dur loads issued before seqs preloads (scan critical path starts first).
//  - len from wtot[] sum; pad-only blocks skip cum LDS write + 2nd barrier.

#define N_ROWS 16
#define T_LEN  2048
#define M_DIM  256
#define M_VEC  (M_DIM / 4)   // 64 float4 per row
#define W_TOK  8             // positions per wave
#define BLK_POS 32           // positions per block (4 waves x 8)

typedef float f32x4 __attribute__((ext_vector_type(4)));

__global__ __launch_bounds__(256) void fused_upsample_kernel(
    const f32x4* __restrict__ seqs4, const int* __restrict__ dur,
    f32x4* __restrict__ out4, float* __restrict__ lens_out, int max_len) {
  const int tid = threadIdx.x;
  const int lane = tid & 63;
  const int wave = tid >> 6;
  const int n = blockIdx.y;
  const int block_base = blockIdx.x * BLK_POS;
  const int p = block_base + wave * W_TOK;
  const bool tok = (block_base < T_LEN);   // block-uniform (T_LEN % 32 == 0)

  // ---- dur loads first: they gate the scan -> stores critical path ----
  const int base = n * T_LEN + tid * 8;
  int4 a = *(const int4*)(dur + base);
  int4 b = *(const int4*)(dur + base + 4);

  const f32x4* __restrict__ srow = seqs4 + (size_t)n * T_LEN * M_VEC + lane;
  f32x4* __restrict__ orow = out4 + (size_t)n * max_len * M_VEC + lane;

  // ---- seqs preloads: 8 independent row loads in flight per wave ----
  f32x4 v[W_TOK];
#pragma unroll
  for (int k = 0; k < W_TOK; ++k) {
    v[k] = (f32x4)0.f;
    if (tok) v[k] = srow[(size_t)(p + k) * M_VEC];
  }

  // ---- block-wide cumsum of this row into LDS ----
  __shared__ int cums[T_LEN];              // 8 KB
  __shared__ int wtot[4];
  int tot = 0;
  a.x = (tot += a.x); a.y = (tot += a.y); a.z = (tot += a.z); a.w = (tot += a.w);
  b.x = (tot += b.x); b.y = (tot += b.y); b.z = (tot += b.z); b.w = (tot += b.w);

  int scan = tot;                          // wave-inclusive scan of totals
#pragma unroll
  for (int d = 1; d < 64; d <<= 1) {
    const int t = __shfl_up(scan, d, 64);
    if (lane >= d) scan += t;
  }
  if (lane == 63) wtot[wave] = scan;
  __syncthreads();
  const int w0 = wtot[0], w1 = wtot[1], w2 = wtot[2], w3 = wtot[3];
  const int len = w0 + w1 + w2 + w3;       // row total

  if (blockIdx.x == 0 && tid == 0) lens_out[n] = (float)len;

  if (tok) {
    int woff = 0;
    if (wave > 0) woff += w0;
    if (wave > 1) woff += w1;
    if (wave > 2) woff += w2;
    const int excl = woff + scan - tot;
    a.x += excl; a.y += excl; a.z += excl; a.w += excl;
    b.x += excl; b.y += excl; b.z += excl; b.w += excl;
    *(int4*)(cums + tid * 8) = a;
    *(int4*)(cums + tid * 8 + 4) = b;
    __syncthreads();

    // ---- scatter: boundaries via LDS broadcast reads ----
    int st[W_TOK], dk[W_TOK];
#pragma unroll
    for (int k = 0; k < W_TOK; ++k) {
      const int c0 = (p + k == 0) ? 0 : cums[p + k - 1];
      const int c1 = cums[p + k];
      st[k] = c0;
      dk[k] = c1 - c0;                     // 0..3
    }
#pragma unroll
    for (int k = 0; k < W_TOK; ++k) {
      if (dk[k] > 0) orow[(size_t)(st[k] + 0) * M_VEC] = v[k];
      if (dk[k] > 1) orow[(size_t)(st[k] + 1) * M_VEC] = v[k];
      if (dk[k] > 2) orow[(size_t)(st[k] + 2) * M_VEC] = v[k];
    }
  }

  // ---- padding: output rows [len, max_len) in this wave's range ----
  const f32x4 z = (f32x4)0.f;
#pragma unroll
  for (int k = 0; k < W_TOK; ++k) {
    const int i = p + k;
    if (i >= len && i < max_len) orow[(size_t)i * M_VEC] = z;
  }
}

extern "C" void kernel_launch(void* const* d_in, const int* in_sizes, int n_in,
                              void* d_out, int out_size, void* d_ws, size_t ws_size,
                              hipStream_t stream) {
  const float* seqs = (const float*)d_in[0];       // [16, 2048, 256] f32
  const int* durations = (const int*)d_in[1];      // [16, 2048] i32
  float* out = (float*)d_out;

  const int N = N_ROWS;
  const int M = M_DIM;
  const int max_len = (out_size - N) / (N * M);    // padded output length L

  float* lens_out = out + (size_t)N * max_len * M; // lens chunk (as f32 values)

  const int span = (max_len > T_LEN) ? max_len : T_LEN;
  dim3 grid((span + BLK_POS - 1) / BLK_POS, N);
  fused_upsample_kernel<<<grid, dim3(256), 0, stream>>>(
      (const f32x4*)seqs, durations, (f32x4*)out, lens_out, max_len);
}

// Round 9
// 18.126 us; speedup vs baseline: 1.3154x; 1.3154x over previous
//
#include <hip/hip_runtime.h>

// HardUpsampling: seqs [N=16, T=2048, M=256] f32, durations [N, T] i32 in [0,4)
// out = concat( upsampled [N, L, M] f32 , lens [N] (written as f32) )
//
// Round 9: R7 body (4-token waves, <=64 VGPR — 8-token waves proved to cross
// the VGPR-64 occupancy cliff in R3/R4/R8) with the grid cut to exactly one
// residency round:
//  - grid = 128 x-blocks x 16 rows = 2048 blocks = 8192 waves = 256 CU x 8
//    blocks -> single scheduling round (R7 had 3136 blocks = 1.53 rounds,
//    1088 of them pad-only yet each paying the full 8KB dur scan).
//  - every block is a token block; the high pad region [T_LEN, max_len) is
//    striped across blocks (~9 positions each, pure zero stores, after len
//    is known from wtot — no extra loads, no extra blocks).

#define N_ROWS 16
#define T_LEN  2048
#define M_DIM  256
#define M_VEC  (M_DIM / 4)   // 64 float4 per row
#define W_TOK  4             // tokens per wave
#define BLK_POS 16           // tokens per block (4 waves x 4)
#define NXB    (T_LEN / BLK_POS)   // 128 x-blocks per row

typedef float f32x4 __attribute__((ext_vector_type(4)));

__global__ __launch_bounds__(256) void fused_upsample_kernel(
    const f32x4* __restrict__ seqs4, const int* __restrict__ dur,
    f32x4* __restrict__ out4, float* __restrict__ lens_out,
    int max_len, int pad_per_blk) {
  const int tid = threadIdx.x;
  const int lane = tid & 63;
  const int wave = tid >> 6;
  const int n = blockIdx.y;
  const int p = blockIdx.x * BLK_POS + wave * W_TOK;   // token base, < T_LEN

  // ---- dur loads first: they gate the scan -> stores critical path ----
  const int base = n * T_LEN + tid * 8;
  int4 a = *(const int4*)(dur + base);
  int4 b = *(const int4*)(dur + base + 4);

  const f32x4* __restrict__ srow = seqs4 + (size_t)n * T_LEN * M_VEC + lane;
  f32x4* __restrict__ orow = out4 + (size_t)n * max_len * M_VEC + lane;

  // ---- seqs preloads: 4 independent row loads in flight per wave ----
  f32x4 v[W_TOK];
#pragma unroll
  for (int k = 0; k < W_TOK; ++k) v[k] = srow[(size_t)(p + k) * M_VEC];

  // ---- block-wide cumsum of this row into LDS ----
  __shared__ int cums[T_LEN];              // 8 KB
  __shared__ int wtot[4];
  int tot = 0;
  a.x = (tot += a.x); a.y = (tot += a.y); a.z = (tot += a.z); a.w = (tot += a.w);
  b.x = (tot += b.x); b.y = (tot += b.y); b.z = (tot += b.z); b.w = (tot += b.w);

  int scan = tot;                          // wave-inclusive scan of totals
#pragma unroll
  for (int d = 1; d < 64; d <<= 1) {
    const int t = __shfl_up(scan, d, 64);
    if (lane >= d) scan += t;
  }
  if (lane == 63) wtot[wave] = scan;
  __syncthreads();
  const int w0 = wtot[0], w1 = wtot[1], w2 = wtot[2], w3 = wtot[3];
  const int len = w0 + w1 + w2 + w3;       // row total

  if (blockIdx.x == 0 && tid == 0) lens_out[n] = (float)len;

  int woff = 0;
  if (wave > 0) woff += w0;
  if (wave > 1) woff += w1;
  if (wave > 2) woff += w2;
  const int excl = woff + scan - tot;
  {
    int4 ca = a, cb = b;
    ca.x += excl; ca.y += excl; ca.z += excl; ca.w += excl;
    cb.x += excl; cb.y += excl; cb.z += excl; cb.w += excl;
    *(int4*)(cums + tid * 8) = ca;
    *(int4*)(cums + tid * 8 + 4) = cb;
  }
  __syncthreads();

  // ---- scatter: boundaries via LDS broadcast reads ----
  int st[W_TOK], dk[W_TOK];
#pragma unroll
  for (int k = 0; k < W_TOK; ++k) {
    const int c0 = (p + k == 0) ? 0 : cums[p + k - 1];
    const int c1 = cums[p + k];
    st[k] = c0;
    dk[k] = c1 - c0;                       // 0..3
  }
#pragma unroll
  for (int k = 0; k < W_TOK; ++k) {
    if (dk[k] > 0) orow[(size_t)(st[k] + 0) * M_VEC] = v[k];
    if (dk[k] > 1) orow[(size_t)(st[k] + 1) * M_VEC] = v[k];
    if (dk[k] > 2) orow[(size_t)(st[k] + 2) * M_VEC] = v[k];
  }

  // ---- padding duty 1: own token range (covers len < T_LEN cases) ----
  const f32x4 z = (f32x4)0.f;
#pragma unroll
  for (int k = 0; k < W_TOK; ++k) {
    const int i = p + k;
    if (i >= len && i < max_len) orow[(size_t)i * M_VEC] = z;
  }

  // ---- padding duty 2: striped share of [T_LEN, max_len) ----
  for (int j = wave; j < pad_per_blk; j += 4) {
    const int i = T_LEN + blockIdx.x * pad_per_blk + j;
    if (i < max_len && i >= len) orow[(size_t)i * M_VEC] = z;
  }
}

extern "C" void kernel_launch(void* const* d_in, const int* in_sizes, int n_in,
                              void* d_out, int out_size, void* d_ws, size_t ws_size,
                              hipStream_t stream) {
  const float* seqs = (const float*)d_in[0];       // [16, 2048, 256] f32
  const int* durations = (const int*)d_in[1];      // [16, 2048] i32
  float* out = (float*)d_out;

  const int N = N_ROWS;
  const int M = M_DIM;
  const int max_len = (out_size - N) / (N * M);    // padded output length L

  float* lens_out = out + (size_t)N * max_len * M; // lens chunk (as f32 values)

  const int pad_span = (max_len > T_LEN) ? (max_len - T_LEN) : 0;
  const int pad_per_blk = (pad_span + NXB - 1) / NXB;

  dim3 grid(NXB, N);                               // 2048 blocks, one round
  fused_upsample_kernel<<<grid, dim3(256), 0, stream>>>(
      (const f32x4*)seqs, durations, (f32x4*)out, lens_out,
      max_len, pad_per_blk);
}